// Round 2
// baseline (175730.286 us; speedup 1.0000x reference)
//
#include <hip/hip_runtime.h>
#include <hip/hip_bf16.h>
#include <math.h>

typedef __hip_bfloat16 bf16;

#define E_ 320
#define K_ 128
#define H_ 10
#define HD_ 32
#define T_ 256
#define TM1_ 255
#define SMAX_ (TM1_*K_)      // 32640
#define CHUNK_ 1024
#define MAXCH_ 32            // ceil(32640/1024)
#define QSCALE 0.17677669529663687f
#define EPS_LN 1e-5f

// ---- dtype-agnostic input load: isbf ? bf16 : f32 ----
__device__ __forceinline__ float ldin(const void* p, size_t i, int isbf){
  if (isbf) return __bfloat162float(((const bf16*)p)[i]);
  return ((const float*)p)[i];
}
__device__ __forceinline__ void stout(void* p, size_t i, float v, int isbf){
  if (isbf) ((bf16*)p)[i] = __float2bfloat16(v);
  else      ((float*)p)[i] = v;
}

__device__ __forceinline__ float ldc(const float* p){ return *p; }
__device__ __forceinline__ float ldc(const bf16* p){ return __bfloat162float(*p); }
__device__ __forceinline__ void stc(float* p, float v){ *p = v; }
__device__ __forceinline__ void stc(bf16* p, float v){ *p = __float2bfloat16(v); }

// block = 320 threads (5 waves). Reduces a and b across the block.
__device__ __forceinline__ void reduce2_320(float& a, float& b, float* sc){
  #pragma unroll
  for (int off = 32; off > 0; off >>= 1){
    a += __shfl_down(a, off, 64);
    b += __shfl_down(b, off, 64);
  }
  int w = threadIdx.x >> 6, lane = threadIdx.x & 63;
  __syncthreads();                 // protect previous use of sc
  if (lane == 0){ sc[w] = a; sc[8+w] = b; }
  __syncthreads();
  a = sc[0]+sc[1]+sc[2]+sc[3]+sc[4];
  b = sc[8]+sc[9]+sc[10]+sc[11]+sc[12];
}

// ---------------- dtype detector ----------------
// If input is f32, even uint16 positions are low mantissa halves -> decoded
// as bf16 they are implausible magnitudes. If input is bf16, they are the
// actual N(0,1) values of mu_0_alpha.
__global__ void detect_kernel(const void* __restrict__ mu0, int* __restrict__ flag){
  int lane = threadIdx.x;   // 64 threads
  const unsigned short* u = (const unsigned short*)mu0;
  int cnt = 0;
  #pragma unroll
  for (int rep = 0; rep < 2; ++rep){
    unsigned short w = u[(size_t)(lane + rep*64) * 2];  // even uint16 position
    float v = __uint_as_float(((unsigned int)w) << 16);
    float a = fabsf(v);
    if (a >= 1e-4f && a <= 64.f) cnt++;
  }
  #pragma unroll
  for (int off = 32; off > 0; off >>= 1) cnt += __shfl_down(cnt, off, 64);
  if (lane == 0) *flag = (cnt >= 64) ? 1 : 0;
}

// ---------------- setup: fused projection weights ----------------
// WcT[i*960 + sec*320 + o] = s(sec) * sum_m in_proj_w[sec*320+o][m] * qkv_w[sec*320+m][i]
__global__ __launch_bounds__(256) void setup_wc(const void* __restrict__ inw,
                                                const void* __restrict__ qkvw,
                                                float* __restrict__ WcT,
                                                const int* __restrict__ flagp){
  const int isbf = *flagp;
  int sec = blockIdx.z;
  int i = blockIdx.y*16 + threadIdx.y;   // 0..319 (output row of WcT)
  int o = blockIdx.x*16 + threadIdx.x;   // 0..319 (col within section)
  __shared__ float As[16][17];
  __shared__ float Bs[16][17];
  float acc = 0.f;
  for (int mt = 0; mt < E_; mt += 16){
    // At[m][o] = inw[(sec*320+o)*320 + m]
    As[threadIdx.y][threadIdx.x] = ldin(inw, ((size_t)(sec*E_ + blockIdx.x*16 + threadIdx.x))*E_ + mt + threadIdx.y, isbf);
    // Bt[i][m] = qkvw[(sec*320+m)*320 + i]
    Bs[threadIdx.y][threadIdx.x] = ldin(qkvw, ((size_t)(sec*E_ + mt + threadIdx.x))*E_ + blockIdx.y*16 + threadIdx.y, isbf);
    __syncthreads();
    #pragma unroll
    for (int mm = 0; mm < 16; ++mm) acc += Bs[threadIdx.y][mm] * As[mm][threadIdx.x];
    __syncthreads();
  }
  if (sec == 0) acc *= QSCALE;
  WcT[(size_t)i*960 + sec*E_ + o] = acc;
}

// bc[c]; owT[i*320+c] = out_w[c*320+i]; f32 copies of outb/lng/lnb
__global__ __launch_bounds__(256) void setup_misc(const void* __restrict__ inw,
                                                  const void* __restrict__ inb,
                                                  const void* __restrict__ qkvb,
                                                  const void* __restrict__ outw,
                                                  const void* __restrict__ outb,
                                                  const void* __restrict__ lng,
                                                  const void* __restrict__ lnb,
                                                  float* __restrict__ bc,
                                                  float* __restrict__ owT,
                                                  float* __restrict__ vec,
                                                  const int* __restrict__ flagp){
  const int isbf = *flagp;
  int id = blockIdx.x*256 + threadIdx.x;
  if (id < 960){
    int sec = id / E_, o = id % E_;
    float acc = 0.f;
    for (int m = 0; m < E_; ++m)
      acc += ldin(inw, ((size_t)(sec*E_+o))*E_ + m, isbf) * ldin(qkvb, sec*E_ + m, isbf);
    acc += ldin(inb, id, isbf);
    if (sec == 0) acc *= QSCALE;
    bc[id] = acc;
  }
  int j = id - 1024;
  if (j >= 0 && j < E_*E_){
    int i = j / E_, c = j % E_;
    owT[(size_t)i*E_ + c] = ldin(outw, (size_t)c*E_ + i, isbf);
  }
  int v = id - (1024 + E_*E_);
  if (v >= 0 && v < 960){
    if (v < 320)       vec[v] = ldin(outb, v, isbf);
    else if (v < 640)  vec[v] = ldin(lng, v - 320, isbf);
    else               vec[v] = ldin(lnb, v - 640, isbf);
  }
}

// ---------------- alpha0 = LN(mu_0_alpha) ----------------
__global__ __launch_bounds__(320) void ln0_kernel(const void* __restrict__ mu0,
                                                  const float* __restrict__ vec,
                                                  float* __restrict__ alpha,
                                                  void* __restrict__ out,
                                                  const int* __restrict__ flagp){
  const int isbf = *flagp;
  int r = blockIdx.x, c = threadIdx.x;
  __shared__ float sc[16];
  float x = ldin(mu0, (size_t)r*E_ + c, isbf);
  float s = x, s2 = x*x;
  reduce2_320(s, s2, sc);
  float mean = s * (1.f/E_);
  float var  = s2 * (1.f/E_) - mean*mean;
  float y = (x - mean) * rsqrtf(var + EPS_LN) * vec[320 + c] + vec[640 + c];
  alpha[(size_t)r*E_ + c] = y;
  stout(out, (size_t)r*E_ + c, y, isbf);
}

// ---------------- per-step: projection ----------------
// P[r][c] = sum_i alpha[r][i]*WcT[i][c] + bc[c];  c<320 -> q2, <640 -> kcache, else vcache
template<typename CT>
__global__ __launch_bounds__(320) void project_kernel(const float* __restrict__ alpha,
                                                      const float* __restrict__ WcT,
                                                      const float* __restrict__ bc,
                                                      float* __restrict__ q2,
                                                      CT* __restrict__ kc,
                                                      CT* __restrict__ vc,
                                                      int t){
  int c = blockIdx.x*320 + threadIdx.x;   // 0..959
  int r0 = blockIdx.y*4;
  __shared__ float sa[4][E_];
  #pragma unroll
  for (int j = 0; j < 4; ++j) sa[j][threadIdx.x] = alpha[(size_t)(r0+j)*E_ + threadIdx.x];
  __syncthreads();
  float a0=0.f, a1=0.f, a2=0.f, a3=0.f;
  for (int i = 0; i < E_; ++i){
    float w = WcT[(size_t)i*960 + c];
    a0 += sa[0][i]*w; a1 += sa[1][i]*w; a2 += sa[2][i]*w; a3 += sa[3][i]*w;
  }
  float bias = bc[c];
  float vals[4] = {a0+bias, a1+bias, a2+bias, a3+bias};
  #pragma unroll
  for (int j = 0; j < 4; ++j){
    int r = r0 + j;
    if (c < E_)            q2[(size_t)r*E_ + c] = vals[j];
    else if (c < 2*E_)     stc(kc + ((size_t)(t*K_ + r))*E_ + (c - E_),   vals[j]);
    else                   stc(vc + ((size_t)(t*K_ + r))*E_ + (c - 2*E_), vals[j]);
  }
}

// ---------------- per-step: attention partials (split-S flash) ----------------
// grid (nchunks, H). block 256 = 2 threads per q-row (each owns 16 of 32 dims).
template<typename CT>
__global__ __launch_bounds__(256) void attn_kernel(const float* __restrict__ q2,
                                                   const CT* __restrict__ kc,
                                                   const CT* __restrict__ vc,
                                                   float* __restrict__ part,
                                                   int S){
  int ci = blockIdx.x, h = blockIdx.y;
  int tid = threadIdx.x;
  int r = tid >> 1, half = tid & 1, d0 = half*16;
  const float* qp = q2 + (size_t)r*E_ + h*HD_ + d0;
  float q[16];
  #pragma unroll
  for (int i = 0; i < 16; ++i) q[i] = qp[i];
  float m = -INFINITY, l = 0.f;
  float o[16];
  #pragma unroll
  for (int i = 0; i < 16; ++i) o[i] = 0.f;
  int s0 = ci*CHUNK_, s1 = min(s0 + CHUNK_, S);
  for (int s = s0; s < s1; ++s){
    const CT* kr = kc + (size_t)s*E_ + h*HD_ + d0;
    float dot = 0.f;
    #pragma unroll
    for (int i = 0; i < 16; ++i) dot += q[i]*ldc(kr+i);
    dot += __shfl_xor(dot, 1, 64);
    float mn = fmaxf(m, dot);
    float corr = __expf(m - mn);
    float p = __expf(dot - mn);
    l = l*corr + p;
    m = mn;
    const CT* vr = vc + (size_t)s*E_ + h*HD_ + d0;
    #pragma unroll
    for (int i = 0; i < 16; ++i) o[i] = o[i]*corr + p*ldc(vr+i);
  }
  size_t base = (((size_t)h*MAXCH_ + ci)*K_ + r)*34;
  if (half == 0){
    part[base] = m; part[base+1] = l;
    #pragma unroll
    for (int i = 0; i < 16; ++i) part[base+2+i] = o[i];
  } else {
    #pragma unroll
    for (int i = 0; i < 16; ++i) part[base+18+i] = o[i];
  }
}

// ---------------- per-step: combine + out-proj + residual + LN ----------------
// grid 32 blocks x 4 rows, block 320.
__global__ __launch_bounds__(320) void combine_kernel(const float* __restrict__ part,
                                                      const float* __restrict__ owT,
                                                      const float* __restrict__ vec,
                                                      float* __restrict__ alpha,
                                                      void* __restrict__ out,
                                                      const int* __restrict__ flagp,
                                                      int t, int nch){
  const int isbf = *flagp;
  int tid = threadIdx.x;
  int r0 = blockIdx.x*4;
  int h = tid >> 5, d = tid & 31;
  __shared__ float s_att[4][E_];
  __shared__ float sc[16];
  for (int j = 0; j < 4; ++j){
    int r = r0 + j;
    float mstar = -INFINITY;
    for (int ci = 0; ci < nch; ++ci)
      mstar = fmaxf(mstar, part[(((size_t)h*MAXCH_ + ci)*K_ + r)*34]);
    float L = 0.f, acc = 0.f;
    for (int ci = 0; ci < nch; ++ci){
      size_t base = (((size_t)h*MAXCH_ + ci)*K_ + r)*34;
      float w = __expf(part[base] - mstar);
      L   += w * part[base+1];
      acc += w * part[base+2+d];
    }
    s_att[j][tid] = acc / L;
  }
  __syncthreads();
  float vb = vec[tid];
  float a0=vb, a1=vb, a2=vb, a3=vb;
  for (int i = 0; i < E_; ++i){
    float w = owT[(size_t)i*E_ + tid];
    a0 += s_att[0][i]*w; a1 += s_att[1][i]*w; a2 += s_att[2][i]*w; a3 += s_att[3][i]*w;
  }
  float g = vec[320 + tid];
  float bb = vec[640 + tid];
  float accs[4] = {a0, a1, a2, a3};
  for (int j = 0; j < 4; ++j){
    int r = r0 + j;
    float x = accs[j] + alpha[(size_t)r*E_ + tid];
    float s = x, s2 = x*x;
    reduce2_320(s, s2, sc);
    float mean = s * (1.f/E_);
    float var  = s2 * (1.f/E_) - mean*mean;
    float y = (x - mean) * rsqrtf(var + EPS_LN) * g + bb;
    alpha[(size_t)r*E_ + tid] = y;
    stout(out, ((size_t)(t+1)*K_ + r)*E_ + tid, y, isbf);
  }
}

extern "C" void kernel_launch(void* const* d_in, const int* in_sizes, int n_in,
                              void* d_out, int out_size, void* d_ws, size_t ws_size,
                              hipStream_t stream){
  const void* mu0  = d_in[0];
  const void* qkvw = d_in[1];
  const void* qkvb = d_in[2];
  const void* inw  = d_in[3];
  const void* inb  = d_in[4];
  const void* outw = d_in[5];
  const void* outb = d_in[6];
  const void* lng  = d_in[7];
  const void* lnb  = d_in[8];
  float* ws = (float*)d_ws;

  // ws layout (float offsets)
  const size_t O_WCT   = 0;                         // 320*960 = 307200
  const size_t O_BC    = 307200;                    // 960 (pad to 1024)
  const size_t O_OWT   = 308224;                    // 320*320 = 102400
  const size_t O_VEC   = 410624;                    // 960 (pad to 1024): outb|lng|lnb
  const size_t O_ALPHA = 411648;                    // 128*320 = 40960
  const size_t O_Q2    = 452608;                    // 40960
  const size_t O_PART  = 493568;                    // 10*32*128*34 = 1392640
  const size_t O_FLAG  = 1886208;                   // 32
  const size_t O_KV    = 1886240;

  float* WcT   = ws + O_WCT;
  float* bc    = ws + O_BC;
  float* owT   = ws + O_OWT;
  float* vec   = ws + O_VEC;
  float* alpha = ws + O_ALPHA;
  float* q2    = ws + O_Q2;
  float* part  = ws + O_PART;
  int*   flag  = (int*)(ws + O_FLAG);

  const size_t kv_elems = (size_t)SMAX_ * E_;       // 10,444,800 per cache
  bool kv32 = ws_size >= (O_KV + 2*kv_elems) * 4ull;

  detect_kernel<<<dim3(1), dim3(64), 0, stream>>>(mu0, flag);
  setup_wc<<<dim3(20,20,3), dim3(16,16), 0, stream>>>(inw, qkvw, WcT, flag);
  setup_misc<<<dim3(408), dim3(256), 0, stream>>>(inw, inb, qkvb, outw, outb, lng, lnb, bc, owT, vec, flag);
  ln0_kernel<<<dim3(128), dim3(320), 0, stream>>>(mu0, vec, alpha, d_out, flag);

  if (kv32){
    float* kc = ws + O_KV;
    float* vc = kc + kv_elems;
    for (int t = 0; t < TM1_; ++t){
      project_kernel<float><<<dim3(3,32), dim3(320), 0, stream>>>(alpha, WcT, bc, q2, kc, vc, t);
      int S = (t+1)*K_;
      int nch = (S + CHUNK_ - 1) / CHUNK_;
      attn_kernel<float><<<dim3(nch, H_), dim3(256), 0, stream>>>(q2, kc, vc, part, S);
      combine_kernel<<<dim3(32), dim3(320), 0, stream>>>(part, owT, vec, alpha, d_out, flag, t, nch);
    }
  } else {
    bf16* kc = (bf16*)(ws + O_KV);
    bf16* vc = kc + kv_elems;
    for (int t = 0; t < TM1_; ++t){
      project_kernel<bf16><<<dim3(3,32), dim3(320), 0, stream>>>(alpha, WcT, bc, q2, kc, vc, t);
      int S = (t+1)*K_;
      int nch = (S + CHUNK_ - 1) / CHUNK_;
      attn_kernel<bf16><<<dim3(nch, H_), dim3(256), 0, stream>>>(q2, kc, vc, part, S);
      combine_kernel<<<dim3(32), dim3(320), 0, stream>>>(part, owT, vec, alpha, d_out, flag, t, nch);
    }
  }
}

// Round 3
// 23876.648 us; speedup vs baseline: 7.3599x; 7.3599x over previous
//
#include <hip/hip_runtime.h>
#include <hip/hip_bf16.h>
#include <math.h>

typedef __hip_bfloat16 bf16;
using short8 = __attribute__((ext_vector_type(8))) short;
using f32x4  = __attribute__((ext_vector_type(4))) float;

#define E_ 320
#define K_ 128
#define H_ 10
#define HD_ 32
#define T_ 256
#define TM1_ 255
#define SMAX_ (TM1_*K_)      // 32640
#define MAXCH_ 32
#define QSCALE 0.17677669529663687f
#define EPS_LN 1e-5f

// ---- dtype-agnostic input load: isbf ? bf16 : f32 ----
__device__ __forceinline__ float ldin(const void* p, size_t i, int isbf){
  if (isbf) return __bfloat162float(((const bf16*)p)[i]);
  return ((const float*)p)[i];
}
__device__ __forceinline__ void stout(void* p, size_t i, float v, int isbf){
  if (isbf) ((bf16*)p)[i] = __float2bfloat16(v);
  else      ((float*)p)[i] = v;
}

// block = 320 threads (5 waves). Reduces a and b across the block.
__device__ __forceinline__ void reduce2_320(float& a, float& b, float* sc){
  #pragma unroll
  for (int off = 32; off > 0; off >>= 1){
    a += __shfl_down(a, off, 64);
    b += __shfl_down(b, off, 64);
  }
  int w = threadIdx.x >> 6, lane = threadIdx.x & 63;
  __syncthreads();
  if (lane == 0){ sc[w] = a; sc[8+w] = b; }
  __syncthreads();
  a = sc[0]+sc[1]+sc[2]+sc[3]+sc[4];
  b = sc[8]+sc[9]+sc[10]+sc[11]+sc[12];
}

// ---------------- dtype detector ----------------
__global__ void detect_kernel(const void* __restrict__ mu0, int* __restrict__ flag){
  int lane = threadIdx.x;
  const unsigned short* u = (const unsigned short*)mu0;
  int cnt = 0;
  #pragma unroll
  for (int rep = 0; rep < 2; ++rep){
    unsigned short w = u[(size_t)(lane + rep*64) * 2];
    float v = __uint_as_float(((unsigned int)w) << 16);
    float a = fabsf(v);
    if (a >= 1e-4f && a <= 64.f) cnt++;
  }
  #pragma unroll
  for (int off = 32; off > 0; off >>= 1) cnt += __shfl_down(cnt, off, 64);
  if (lane == 0) *flag = (cnt >= 64) ? 1 : 0;
}

// ---------------- setup: fused projection weights ----------------
// WcT[i*960 + sec*320 + o] = s(sec) * sum_m in_proj_w[sec*320+o][m] * qkv_w[sec*320+m][i]
__global__ __launch_bounds__(256) void setup_wc(const void* __restrict__ inw,
                                                const void* __restrict__ qkvw,
                                                float* __restrict__ WcT,
                                                const int* __restrict__ flagp){
  const int isbf = *flagp;
  int sec = blockIdx.z;
  int i = blockIdx.y*16 + threadIdx.y;
  int o = blockIdx.x*16 + threadIdx.x;
  __shared__ float As[16][17];
  __shared__ float Bs[16][17];
  float acc = 0.f;
  for (int mt = 0; mt < E_; mt += 16){
    As[threadIdx.y][threadIdx.x] = ldin(inw, ((size_t)(sec*E_ + blockIdx.x*16 + threadIdx.x))*E_ + mt + threadIdx.y, isbf);
    Bs[threadIdx.y][threadIdx.x] = ldin(qkvw, ((size_t)(sec*E_ + mt + threadIdx.x))*E_ + blockIdx.y*16 + threadIdx.y, isbf);
    __syncthreads();
    #pragma unroll
    for (int mm = 0; mm < 16; ++mm) acc += Bs[threadIdx.y][mm] * As[mm][threadIdx.x];
    __syncthreads();
  }
  if (sec == 0) acc *= QSCALE;
  WcT[(size_t)i*960 + sec*E_ + o] = acc;
}

// bc[c]; owT[i*320+c] = out_w[c*320+i]; f32 copies of outb/lng/lnb
__global__ __launch_bounds__(256) void setup_misc(const void* __restrict__ inw,
                                                  const void* __restrict__ inb,
                                                  const void* __restrict__ qkvb,
                                                  const void* __restrict__ outw,
                                                  const void* __restrict__ outb,
                                                  const void* __restrict__ lng,
                                                  const void* __restrict__ lnb,
                                                  float* __restrict__ bc,
                                                  float* __restrict__ owT,
                                                  float* __restrict__ vec,
                                                  const int* __restrict__ flagp){
  const int isbf = *flagp;
  int id = blockIdx.x*256 + threadIdx.x;
  if (id < 960){
    int sec = id / E_, o = id % E_;
    float acc = 0.f;
    for (int m = 0; m < E_; ++m)
      acc += ldin(inw, ((size_t)(sec*E_+o))*E_ + m, isbf) * ldin(qkvb, sec*E_ + m, isbf);
    acc += ldin(inb, id, isbf);
    if (sec == 0) acc *= QSCALE;
    bc[id] = acc;
  }
  int j = id - 1024;
  if (j >= 0 && j < E_*E_){
    int i = j / E_, c = j % E_;
    owT[(size_t)i*E_ + c] = ldin(outw, (size_t)c*E_ + i, isbf);
  }
  int v = id - (1024 + E_*E_);
  if (v >= 0 && v < 960){
    if (v < 320)       vec[v] = ldin(outb, v, isbf);
    else if (v < 640)  vec[v] = ldin(lng, v - 320, isbf);
    else               vec[v] = ldin(lnb, v - 640, isbf);
  }
}

// ---------------- alpha0 = LN(mu_0_alpha) ----------------
__global__ __launch_bounds__(320) void ln0_kernel(const void* __restrict__ mu0,
                                                  const float* __restrict__ vec,
                                                  float* __restrict__ alpha,
                                                  void* __restrict__ out,
                                                  const int* __restrict__ flagp){
  const int isbf = *flagp;
  int r = blockIdx.x, c = threadIdx.x;
  __shared__ float sc[16];
  float x = ldin(mu0, (size_t)r*E_ + c, isbf);
  float s = x, s2 = x*x;
  reduce2_320(s, s2, sc);
  float mean = s * (1.f/E_);
  float var  = s2 * (1.f/E_) - mean*mean;
  float y = (x - mean) * rsqrtf(var + EPS_LN) * vec[320 + c] + vec[640 + c];
  alpha[(size_t)r*E_ + c] = y;
  stout(out, (size_t)r*E_ + c, y, isbf);
}

// ---------------- per-step: projection ----------------
// P[r][c] = sum_i alpha[r][i]*WcT[i][c] + bc[c]
// c<320 -> q2 (bf16), <640 -> K cache (bf16, row-major), else Vt cache (bf16, transposed)
__global__ __launch_bounds__(320) void project_kernel(const float* __restrict__ alpha,
                                                      const float* __restrict__ WcT,
                                                      const float* __restrict__ bc,
                                                      bf16* __restrict__ q2b,
                                                      bf16* __restrict__ kcb,
                                                      bf16* __restrict__ vtb,
                                                      int t){
  int c = blockIdx.x*320 + threadIdx.x;   // 0..959
  int r0 = blockIdx.y*4;
  __shared__ float sa[4][E_];
  #pragma unroll
  for (int j = 0; j < 4; ++j) sa[j][threadIdx.x] = alpha[(size_t)(r0+j)*E_ + threadIdx.x];
  __syncthreads();
  float a0=0.f, a1=0.f, a2=0.f, a3=0.f;
  for (int i = 0; i < E_; ++i){
    float w = WcT[(size_t)i*960 + c];
    a0 += sa[0][i]*w; a1 += sa[1][i]*w; a2 += sa[2][i]*w; a3 += sa[3][i]*w;
  }
  float bias = bc[c];
  float vals[4] = {a0+bias, a1+bias, a2+bias, a3+bias};
  if (c < E_){
    #pragma unroll
    for (int j = 0; j < 4; ++j) q2b[(size_t)(r0+j)*E_ + c] = __float2bfloat16(vals[j]);
  } else if (c < 2*E_){
    #pragma unroll
    for (int j = 0; j < 4; ++j) kcb[((size_t)(t*K_ + r0+j))*E_ + (c - E_)] = __float2bfloat16(vals[j]);
  } else {
    #pragma unroll
    for (int j = 0; j < 4; ++j) vtb[(size_t)(c - 2*E_)*SMAX_ + (size_t)t*K_ + r0+j] = __float2bfloat16(vals[j]);
  }
}

// ---------------- per-step: MFMA flash-attention partials ----------------
// grid (nchU, H). block 256 = 4 waves; wave w owns q-rows [32w, 32w+32).
// mfma_f32_16x16x32_bf16 layouts (HW-verified):
//   C/D: col=lane&15, row=(lane>>4)*4+reg
//   A:   A[m=lane&15][k=(lane>>4)*8+j]
//   B:   B[k=(lane>>4)*8+j][n=lane&15]
__global__ __launch_bounds__(256) void attn_mfma(const bf16* __restrict__ q2b,
                                                 const bf16* __restrict__ kcb,
                                                 const bf16* __restrict__ vtb,
                                                 float* __restrict__ part,
                                                 int S, int chunkS){
  int ci = blockIdx.x, h = blockIdx.y;
  int w    = threadIdx.x >> 6;
  int lane = threadIdx.x & 63;
  int cn   = lane & 15;          // n/col index
  int quad = lane >> 4;          // 0..3
  __shared__ bf16 pbuf[4][16][40];  // per-wave P tile, stride 40 bf16 (80B rows)

  int s0 = ci*chunkS, s1 = min(s0 + chunkS, S);

  // Q A-frags for q-tiles 2w, 2w+1: lane holds Q[m=cn][k=quad*8..+7]
  short8 qf[2];
  #pragma unroll
  for (int qt = 0; qt < 2; ++qt){
    int q = (2*w + qt)*16 + cn;
    qf[qt] = *(const short8*)(const void*)(q2b + (size_t)q*E_ + h*HD_ + quad*8);
  }

  f32x4 acc[2][2];   // [q-tile][d-tile]
  float mrow[2][4], lrow[2][4];
  #pragma unroll
  for (int qt = 0; qt < 2; ++qt){
    #pragma unroll
    for (int dt = 0; dt < 2; ++dt) acc[qt][dt] = (f32x4){0.f,0.f,0.f,0.f};
    #pragma unroll
    for (int r = 0; r < 4; ++r){ mrow[qt][r] = -INFINITY; lrow[qt][r] = 0.f; }
  }

  for (int sb = s0; sb < s1; sb += 32){
    // K B-frags: lane holds K[s=sb+st*16+cn][d=quad*8..+7]
    short8 kf0 = *(const short8*)(const void*)(kcb + (size_t)(sb +      cn)*E_ + h*HD_ + quad*8);
    short8 kf1 = *(const short8*)(const void*)(kcb + (size_t)(sb + 16 + cn)*E_ + h*HD_ + quad*8);
    // V B-frags: lane holds V[s=sb+quad*8..+7][d=dt*16+cn] from Vt[d][s]
    short8 vf0 = *(const short8*)(const void*)(vtb + (size_t)(h*HD_ +      cn)*SMAX_ + sb + quad*8);
    short8 vf1 = *(const short8*)(const void*)(vtb + (size_t)(h*HD_ + 16 + cn)*SMAX_ + sb + quad*8);
    f32x4 z = (f32x4){0.f,0.f,0.f,0.f};
    #pragma unroll
    for (int qt = 0; qt < 2; ++qt){
      f32x4 sA = __builtin_amdgcn_mfma_f32_16x16x32_bf16(qf[qt], kf0, z, 0, 0, 0);
      f32x4 sB = __builtin_amdgcn_mfma_f32_16x16x32_bf16(qf[qt], kf1, z, 0, 0, 0);
      // online softmax per q-row (row = quad*4+r, cols = cn / 16+cn)
      #pragma unroll
      for (int r = 0; r < 4; ++r){
        float mx = fmaxf(sA[r], sB[r]);
        mx = fmaxf(mx, __shfl_xor(mx, 1));
        mx = fmaxf(mx, __shfl_xor(mx, 2));
        mx = fmaxf(mx, __shfl_xor(mx, 4));
        mx = fmaxf(mx, __shfl_xor(mx, 8));
        float mo = mrow[qt][r];
        float mn = fmaxf(mo, mx);
        float corr = __expf(mo - mn);
        mrow[qt][r] = mn;
        float pa = __expf(sA[r] - mn);
        float pb = __expf(sB[r] - mn);
        float ps = pa + pb;
        ps += __shfl_xor(ps, 1);
        ps += __shfl_xor(ps, 2);
        ps += __shfl_xor(ps, 4);
        ps += __shfl_xor(ps, 8);
        lrow[qt][r] = lrow[qt][r]*corr + ps;
        acc[qt][0][r] *= corr;
        acc[qt][1][r] *= corr;
        pbuf[w][quad*4 + r][cn]      = __float2bfloat16(pa);
        pbuf[w][quad*4 + r][16 + cn] = __float2bfloat16(pb);
      }
      // wave-local LDS transpose: C-layout -> A-layout
      asm volatile("s_waitcnt lgkmcnt(0)" ::: "memory");
      short8 pf = *(const short8*)(const void*)(&pbuf[w][cn][quad*8]);
      acc[qt][0] = __builtin_amdgcn_mfma_f32_16x16x32_bf16(pf, vf0, acc[qt][0], 0, 0, 0);
      acc[qt][1] = __builtin_amdgcn_mfma_f32_16x16x32_bf16(pf, vf1, acc[qt][1], 0, 0, 0);
    }
  }

  // write partials {m, l, o[32]} per q-row
  #pragma unroll
  for (int qt = 0; qt < 2; ++qt){
    #pragma unroll
    for (int r = 0; r < 4; ++r){
      int q = (2*w + qt)*16 + quad*4 + r;
      size_t base = (((size_t)h*MAXCH_ + ci)*K_ + q)*34;
      if (cn == 0){ part[base] = mrow[qt][r]; part[base+1] = lrow[qt][r]; }
      part[base + 2 + cn]  = acc[qt][0][r];
      part[base + 18 + cn] = acc[qt][1][r];
    }
  }
}

// ---------------- per-step: combine + out-proj + residual + LN ----------------
// grid 64 blocks x 2 rows, block 320.
__global__ __launch_bounds__(320) void combine_kernel(const float* __restrict__ part,
                                                      const float* __restrict__ owT,
                                                      const float* __restrict__ vec,
                                                      float* __restrict__ alpha,
                                                      void* __restrict__ out,
                                                      const int* __restrict__ flagp,
                                                      int t, int nch){
  const int isbf = *flagp;
  int tid = threadIdx.x;
  int r0 = blockIdx.x*2;
  int h = tid >> 5, d = tid & 31;
  __shared__ float s_att[2][E_];
  __shared__ float sc[16];
  #pragma unroll
  for (int j = 0; j < 2; ++j){
    int r = r0 + j;
    float mstar = -INFINITY;
    for (int ci = 0; ci < nch; ++ci)
      mstar = fmaxf(mstar, part[(((size_t)h*MAXCH_ + ci)*K_ + r)*34]);
    float L = 0.f, acc = 0.f;
    for (int ci = 0; ci < nch; ++ci){
      size_t base = (((size_t)h*MAXCH_ + ci)*K_ + r)*34;
      float w = __expf(part[base] - mstar);
      L   += w * part[base+1];
      acc += w * part[base+2+d];
    }
    s_att[j][tid] = acc / L;
  }
  __syncthreads();
  float vb = vec[tid];
  float a0 = vb, a1 = vb;
  for (int i = 0; i < E_; ++i){
    float w = owT[(size_t)i*E_ + tid];
    a0 += s_att[0][i]*w; a1 += s_att[1][i]*w;
  }
  float g = vec[320 + tid];
  float bb = vec[640 + tid];
  float accs[2] = {a0, a1};
  #pragma unroll
  for (int j = 0; j < 2; ++j){
    int r = r0 + j;
    float x = accs[j] + alpha[(size_t)r*E_ + tid];
    float s = x, s2 = x*x;
    reduce2_320(s, s2, sc);
    float mean = s * (1.f/E_);
    float var  = s2 * (1.f/E_) - mean*mean;
    float y = (x - mean) * rsqrtf(var + EPS_LN) * g + bb;
    alpha[(size_t)r*E_ + tid] = y;
    stout(out, ((size_t)(t+1)*K_ + r)*E_ + tid, y, isbf);
  }
}

extern "C" void kernel_launch(void* const* d_in, const int* in_sizes, int n_in,
                              void* d_out, int out_size, void* d_ws, size_t ws_size,
                              hipStream_t stream){
  const void* mu0  = d_in[0];
  const void* qkvw = d_in[1];
  const void* qkvb = d_in[2];
  const void* inw  = d_in[3];
  const void* inb  = d_in[4];
  const void* outw = d_in[5];
  const void* outb = d_in[6];
  const void* lng  = d_in[7];
  const void* lnb  = d_in[8];
  float* ws = (float*)d_ws;

  // ws layout (float offsets), all 16B-aligned
  const size_t O_WCT   = 0;         // 307200
  const size_t O_BC    = 307200;    // 1024
  const size_t O_OWT   = 308224;    // 102400
  const size_t O_VEC   = 410624;    // 1024
  const size_t O_ALPHA = 411648;    // 40960
  const size_t O_PART  = 452608;    // 10*32*128*34 = 1392640
  const size_t O_FLAG  = 1845248;   // 32
  const size_t O_Q2    = 1845280;   // 128*320 bf16 = 20480 floats
  const size_t O_KC    = 1865760;   // SMAX*320 bf16 = 5222400 floats
  const size_t O_VT    = 7088160;   // SMAX*320 bf16 = 5222400 floats
  // end = 12310560 floats = 49.24 MB

  float* WcT   = ws + O_WCT;
  float* bc    = ws + O_BC;
  float* owT   = ws + O_OWT;
  float* vec   = ws + O_VEC;
  float* alpha = ws + O_ALPHA;
  float* part  = ws + O_PART;
  int*   flag  = (int*)(ws + O_FLAG);
  bf16*  q2b   = (bf16*)(ws + O_Q2);
  bf16*  kcb   = (bf16*)(ws + O_KC);
  bf16*  vtb   = (bf16*)(ws + O_VT);

  detect_kernel<<<dim3(1), dim3(64), 0, stream>>>(mu0, flag);
  setup_wc<<<dim3(20,20,3), dim3(16,16), 0, stream>>>(inw, qkvw, WcT, flag);
  setup_misc<<<dim3(408), dim3(256), 0, stream>>>(inw, inb, qkvb, outw, outb, lng, lnb, bc, owT, vec, flag);
  ln0_kernel<<<dim3(128), dim3(320), 0, stream>>>(mu0, vec, alpha, d_out, flag);

  for (int t = 0; t < TM1_; ++t){
    project_kernel<<<dim3(3,32), dim3(320), 0, stream>>>(alpha, WcT, bc, q2b, kcb, vtb, t);
    int S = (t+1)*K_;
    int nch = (S + 255) / 256; if (nch > MAXCH_) nch = MAXCH_;
    int chunkS = (((S + nch - 1)/nch) + 127) / 128 * 128;
    int nchU = (S + chunkS - 1) / chunkS;
    attn_mfma<<<dim3(nchU, H_), dim3(256), 0, stream>>>(q2b, kcb, vtb, part, S, chunkS);
    combine_kernel<<<dim3(64), dim3(320), 0, stream>>>(part, owT, vec, alpha, d_out, flag, t, nchU);
  }
}

// Round 4
// 19164.250 us; speedup vs baseline: 9.1697x; 1.2459x over previous
//
#include <hip/hip_runtime.h>
#include <hip/hip_bf16.h>
#include <math.h>

typedef __hip_bfloat16 bf16;
using short4v = __attribute__((ext_vector_type(4))) short;
using short8 = __attribute__((ext_vector_type(8))) short;
using f32x4  = __attribute__((ext_vector_type(4))) float;

#define E_ 320
#define K_ 128
#define H_ 10
#define HD_ 32
#define T_ 256
#define TM1_ 255
#define SMAX_ (TM1_*K_)      // 32640
#define MAXCH_ 30
#define QSCALE 0.17677669529663687f
#define EPS_LN 1e-5f

// ---- dtype-agnostic input load: isbf ? bf16 : f32 ----
__device__ __forceinline__ float ldin(const void* p, size_t i, int isbf){
  if (isbf) return __bfloat162float(((const bf16*)p)[i]);
  return ((const float*)p)[i];
}
__device__ __forceinline__ void stout(void* p, size_t i, float v, int isbf){
  if (isbf) ((bf16*)p)[i] = __float2bfloat16(v);
  else      ((float*)p)[i] = v;
}

// block = 320 threads (5 waves). Reduces a and b across the block.
__device__ __forceinline__ void reduce2_320(float& a, float& b, float* sc){
  #pragma unroll
  for (int off = 32; off > 0; off >>= 1){
    a += __shfl_down(a, off, 64);
    b += __shfl_down(b, off, 64);
  }
  int w = threadIdx.x >> 6, lane = threadIdx.x & 63;
  __syncthreads();
  if (lane == 0){ sc[w] = a; sc[8+w] = b; }
  __syncthreads();
  a = sc[0]+sc[1]+sc[2]+sc[3]+sc[4];
  b = sc[8]+sc[9]+sc[10]+sc[11]+sc[12];
}

// ---------------- dtype detector ----------------
__global__ void detect_kernel(const void* __restrict__ mu0, int* __restrict__ flag){
  int lane = threadIdx.x;
  const unsigned short* u = (const unsigned short*)mu0;
  int cnt = 0;
  #pragma unroll
  for (int rep = 0; rep < 2; ++rep){
    unsigned short w = u[(size_t)(lane + rep*64) * 2];
    float v = __uint_as_float(((unsigned int)w) << 16);
    float a = fabsf(v);
    if (a >= 1e-4f && a <= 64.f) cnt++;
  }
  #pragma unroll
  for (int off = 32; off > 0; off >>= 1) cnt += __shfl_down(cnt, off, 64);
  if (lane == 0) *flag = (cnt >= 64) ? 1 : 0;
}

// ---------------- setup: fused projection weights ----------------
__global__ __launch_bounds__(256) void setup_wc(const void* __restrict__ inw,
                                                const void* __restrict__ qkvw,
                                                float* __restrict__ WcT,
                                                const int* __restrict__ flagp){
  const int isbf = *flagp;
  int sec = blockIdx.z;
  int i = blockIdx.y*16 + threadIdx.y;
  int o = blockIdx.x*16 + threadIdx.x;
  __shared__ float As[16][17];
  __shared__ float Bs[16][17];
  float acc = 0.f;
  for (int mt = 0; mt < E_; mt += 16){
    As[threadIdx.y][threadIdx.x] = ldin(inw, ((size_t)(sec*E_ + blockIdx.x*16 + threadIdx.x))*E_ + mt + threadIdx.y, isbf);
    Bs[threadIdx.y][threadIdx.x] = ldin(qkvw, ((size_t)(sec*E_ + mt + threadIdx.x))*E_ + blockIdx.y*16 + threadIdx.y, isbf);
    __syncthreads();
    #pragma unroll
    for (int mm = 0; mm < 16; ++mm) acc += Bs[threadIdx.y][mm] * As[mm][threadIdx.x];
    __syncthreads();
  }
  if (sec == 0) acc *= QSCALE;
  WcT[(size_t)i*960 + sec*E_ + o] = acc;
}

__global__ __launch_bounds__(256) void setup_misc(const void* __restrict__ inw,
                                                  const void* __restrict__ inb,
                                                  const void* __restrict__ qkvb,
                                                  const void* __restrict__ outw,
                                                  const void* __restrict__ outb,
                                                  const void* __restrict__ lng,
                                                  const void* __restrict__ lnb,
                                                  float* __restrict__ bc,
                                                  float* __restrict__ owT,
                                                  float* __restrict__ vec,
                                                  const int* __restrict__ flagp){
  const int isbf = *flagp;
  int id = blockIdx.x*256 + threadIdx.x;
  if (id < 960){
    int sec = id / E_, o = id % E_;
    float acc = 0.f;
    for (int m = 0; m < E_; ++m)
      acc += ldin(inw, ((size_t)(sec*E_+o))*E_ + m, isbf) * ldin(qkvb, sec*E_ + m, isbf);
    acc += ldin(inb, id, isbf);
    if (sec == 0) acc *= QSCALE;
    bc[id] = acc;
  }
  int j = id - 1024;
  if (j >= 0 && j < E_*E_){
    int i = j / E_, c = j % E_;
    owT[(size_t)i*E_ + c] = ldin(outw, (size_t)c*E_ + i, isbf);
  }
  int v = id - (1024 + E_*E_);
  if (v >= 0 && v < 960){
    if (v < 320)       vec[v] = ldin(outb, v, isbf);
    else if (v < 640)  vec[v] = ldin(lng, v - 320, isbf);
    else               vec[v] = ldin(lnb, v - 640, isbf);
  }
}

// ---------------- alpha0 = LN(mu_0_alpha) ----------------
__global__ __launch_bounds__(320) void ln0_kernel(const void* __restrict__ mu0,
                                                  const float* __restrict__ vec,
                                                  float* __restrict__ alpha,
                                                  void* __restrict__ out,
                                                  const int* __restrict__ flagp){
  const int isbf = *flagp;
  int r = blockIdx.x, c = threadIdx.x;
  __shared__ float sc[16];
  float x = ldin(mu0, (size_t)r*E_ + c, isbf);
  float s = x, s2 = x*x;
  reduce2_320(s, s2, sc);
  float mean = s * (1.f/E_);
  float var  = s2 * (1.f/E_) - mean*mean;
  float y = (x - mean) * rsqrtf(var + EPS_LN) * vec[320 + c] + vec[640 + c];
  alpha[(size_t)r*E_ + c] = y;
  stout(out, (size_t)r*E_ + c, y, isbf);
}

// ---------------- per-step: projection ----------------
__global__ __launch_bounds__(320) void project_kernel(const float* __restrict__ alpha,
                                                      const float* __restrict__ WcT,
                                                      const float* __restrict__ bc,
                                                      bf16* __restrict__ q2b,
                                                      bf16* __restrict__ kcb,
                                                      bf16* __restrict__ vtb,
                                                      int t){
  int c = blockIdx.x*320 + threadIdx.x;   // 0..959
  int r0 = blockIdx.y*4;
  __shared__ float sa[4][E_];
  #pragma unroll
  for (int j = 0; j < 4; ++j) sa[j][threadIdx.x] = alpha[(size_t)(r0+j)*E_ + threadIdx.x];
  __syncthreads();
  float a0=0.f, a1=0.f, a2=0.f, a3=0.f;
  for (int i = 0; i < E_; ++i){
    float w = WcT[(size_t)i*960 + c];
    a0 += sa[0][i]*w; a1 += sa[1][i]*w; a2 += sa[2][i]*w; a3 += sa[3][i]*w;
  }
  float bias = bc[c];
  float vals[4] = {a0+bias, a1+bias, a2+bias, a3+bias};
  if (c < E_){
    #pragma unroll
    for (int j = 0; j < 4; ++j) q2b[(size_t)(r0+j)*E_ + c] = __float2bfloat16(vals[j]);
  } else if (c < 2*E_){
    #pragma unroll
    for (int j = 0; j < 4; ++j) kcb[((size_t)(t*K_ + r0+j))*E_ + (c - E_)] = __float2bfloat16(vals[j]);
  } else {
    #pragma unroll
    for (int j = 0; j < 4; ++j) vtb[(size_t)(c - 2*E_)*SMAX_ + (size_t)t*K_ + r0+j] = __float2bfloat16(vals[j]);
  }
}

// ---------------- per-step: MFMA flash-attention partials (transposed S) ----------------
// grid (nchU, H). block 512 = 8 waves; wave w owns q-tile w (q rows 16w..16w+15).
// S^T = K·Q^T : A=K (m=s,k=d), B=Q^T (k=d,n=q)  -> C[row=s-local=quad*4+r][col=q=cn]
// O^T = V^T·P^T : A=V^T (m=d,k=s), B=P^T (k=s,n=q) -> C[row=d-local][col=q]
// Softmax over s = in-lane (8 regs) + shfl xor16/32. No per-row shuffle storm.
__global__ __launch_bounds__(512) void attn_mfma(const bf16* __restrict__ q2b,
                                                 const bf16* __restrict__ kcb,
                                                 const bf16* __restrict__ vtb,
                                                 float* __restrict__ part,
                                                 int S, int chunkS){
  int ci = blockIdx.x, h = blockIdx.y;
  int w    = threadIdx.x >> 6;
  int lane = threadIdx.x & 63;
  int cn   = lane & 15;
  int quad = lane >> 4;
  __shared__ bf16 pbuf[8][16][40];   // [wave][q-local][s-local padded]

  int s0 = ci*chunkS, s1 = min(s0 + chunkS, S);

  // Q as B-frag: B[k=d=quad*8+j][n=q=cn] = Q[16w+cn][quad*8+j]
  short8 qf = *(const short8*)(const void*)(q2b + (size_t)(w*16 + cn)*E_ + h*HD_ + quad*8);

  f32x4 accT[2];                     // [d-tile]: O^T[d=dt*16+quad*4+r][q=16w+cn]
  accT[0] = (f32x4){0.f,0.f,0.f,0.f};
  accT[1] = (f32x4){0.f,0.f,0.f,0.f};
  float mcol = -INFINITY, lcol = 0.f;

  for (int sb = s0; sb < s1; sb += 32){
    // K as A-frags: A[m=s-local=cn][k=d=quad*8+j]
    short8 kf0 = *(const short8*)(const void*)(kcb + (size_t)(sb +      cn)*E_ + h*HD_ + quad*8);
    short8 kf1 = *(const short8*)(const void*)(kcb + (size_t)(sb + 16 + cn)*E_ + h*HD_ + quad*8);
    // V^T as A-frags: A[m=d-local=cn][k=s-local=quad*8+j]
    short8 vf0 = *(const short8*)(const void*)(vtb + (size_t)(h*HD_ +      cn)*SMAX_ + sb + quad*8);
    short8 vf1 = *(const short8*)(const void*)(vtb + (size_t)(h*HD_ + 16 + cn)*SMAX_ + sb + quad*8);
    f32x4 z = (f32x4){0.f,0.f,0.f,0.f};
    f32x4 sT0 = __builtin_amdgcn_mfma_f32_16x16x32_bf16(kf0, qf, z, 0, 0, 0);  // s = sb+quad*4+r
    f32x4 sT1 = __builtin_amdgcn_mfma_f32_16x16x32_bf16(kf1, qf, z, 0, 0, 0);  // s = sb+16+quad*4+r

    // max over this tile's 32 s for column q=cn
    float mx = fmaxf(fmaxf(fmaxf(sT0[0], sT0[1]), fmaxf(sT0[2], sT0[3])),
                     fmaxf(fmaxf(sT1[0], sT1[1]), fmaxf(sT1[2], sT1[3])));
    mx = fmaxf(mx, __shfl_xor(mx, 16, 64));
    mx = fmaxf(mx, __shfl_xor(mx, 32, 64));
    float mn = fmaxf(mcol, mx);
    float corr = __expf(mcol - mn);
    mcol = mn;

    float p0[4], p1[4];
    #pragma unroll
    for (int r = 0; r < 4; ++r){ p0[r] = __expf(sT0[r] - mn); p1[r] = __expf(sT1[r] - mn); }
    float ps = (p0[0]+p0[1]) + (p0[2]+p0[3]) + (p1[0]+p1[1]) + (p1[2]+p1[3]);
    ps += __shfl_xor(ps, 16, 64);
    ps += __shfl_xor(ps, 32, 64);
    lcol = lcol*corr + ps;
    accT[0] *= corr;
    accT[1] *= corr;

    // P in [q][s] layout: lane writes P[q=cn][s=quad*4..+3] and [16+quad*4..+3]
    union { short4v v; bf16 e[4]; } u0, u1;
    #pragma unroll
    for (int r = 0; r < 4; ++r){ u0.e[r] = __float2bfloat16(p0[r]); u1.e[r] = __float2bfloat16(p1[r]); }
    *(short4v*)(void*)(&pbuf[w][cn][quad*4])      = u0.v;
    *(short4v*)(void*)(&pbuf[w][cn][16 + quad*4]) = u1.v;
    asm volatile("s_waitcnt lgkmcnt(0)" ::: "memory");
    // P^T as B-frag: B[k=s=quad*8+j][n=q=cn] = pbuf[cn][quad*8..+7] (16B contiguous)
    short8 pf = *(const short8*)(const void*)(&pbuf[w][cn][quad*8]);
    accT[0] = __builtin_amdgcn_mfma_f32_16x16x32_bf16(vf0, pf, accT[0], 0, 0, 0);
    accT[1] = __builtin_amdgcn_mfma_f32_16x16x32_bf16(vf1, pf, accT[1], 0, 0, 0);
  }

  // partials: layout [h][ci][q][36] = { o[0..31], m, l }
  size_t base = (((size_t)h*MAXCH_ + ci)*K_ + 16*w + cn)*36;
  *(f32x4*)(part + base + quad*4)      = accT[0];
  *(f32x4*)(part + base + 16 + quad*4) = accT[1];
  if (quad == 0){ part[base + 32] = mcol; part[base + 33] = lcol; }
}

// ---------------- per-step: combine + out-proj + residual + LN ----------------
// grid 128 blocks x 1 row, block 320.
__global__ __launch_bounds__(320) void combine_kernel(const float* __restrict__ part,
                                                      const float* __restrict__ owT,
                                                      const float* __restrict__ vec,
                                                      float* __restrict__ alpha,
                                                      void* __restrict__ out,
                                                      const int* __restrict__ flagp,
                                                      int t, int nch){
  const int isbf = *flagp;
  int tid = threadIdx.x;
  int r = blockIdx.x;
  int h = tid >> 5, d = tid & 31;
  __shared__ float s_att[E_];
  __shared__ float sc[16];
  float mstar = -INFINITY;
  for (int ci = 0; ci < nch; ++ci)
    mstar = fmaxf(mstar, part[(((size_t)h*MAXCH_ + ci)*K_ + r)*36 + 32]);
  float L = 0.f, acc = 0.f;
  for (int ci = 0; ci < nch; ++ci){
    size_t base = (((size_t)h*MAXCH_ + ci)*K_ + r)*36;
    float wgt = __expf(part[base+32] - mstar);
    L   += wgt * part[base+33];
    acc += wgt * part[base+d];
  }
  s_att[tid] = acc / L;
  __syncthreads();
  float a0 = vec[tid];
  for (int i = 0; i < E_; ++i) a0 += s_att[i]*owT[(size_t)i*E_ + tid];
  float g = vec[320 + tid];
  float bb = vec[640 + tid];
  float x = a0 + alpha[(size_t)r*E_ + tid];
  float s = x, s2 = x*x;
  reduce2_320(s, s2, sc);
  float mean = s * (1.f/E_);
  float var  = s2 * (1.f/E_) - mean*mean;
  float y = (x - mean) * rsqrtf(var + EPS_LN) * g + bb;
  alpha[(size_t)r*E_ + tid] = y;
  stout(out, ((size_t)(t+1)*K_ + r)*E_ + tid, y, isbf);
}

extern "C" void kernel_launch(void* const* d_in, const int* in_sizes, int n_in,
                              void* d_out, int out_size, void* d_ws, size_t ws_size,
                              hipStream_t stream){
  const void* mu0  = d_in[0];
  const void* qkvw = d_in[1];
  const void* qkvb = d_in[2];
  const void* inw  = d_in[3];
  const void* inb  = d_in[4];
  const void* outw = d_in[5];
  const void* outb = d_in[6];
  const void* lng  = d_in[7];
  const void* lnb  = d_in[8];
  float* ws = (float*)d_ws;

  // ws layout (float offsets), all 16B-aligned
  const size_t O_WCT   = 0;         // 307200
  const size_t O_BC    = 307200;    // 1024
  const size_t O_OWT   = 308224;    // 102400
  const size_t O_VEC   = 410624;    // 1024
  const size_t O_ALPHA = 411648;    // 40960
  const size_t O_PART  = 452608;    // 10*30*128*36 = 1382400
  const size_t O_FLAG  = 1835008;   // 32
  const size_t O_Q2    = 1835040;   // 128*320 bf16 = 20480 floats
  const size_t O_KC    = 1855520;   // SMAX*320 bf16 = 5222400 floats
  const size_t O_VT    = 7077920;   // SMAX*320 bf16 = 5222400 floats
  // end = 12300320 floats = 49.2 MB (<= previous passing footprint)

  float* WcT   = ws + O_WCT;
  float* bc    = ws + O_BC;
  float* owT   = ws + O_OWT;
  float* vec   = ws + O_VEC;
  float* alpha = ws + O_ALPHA;
  float* part  = ws + O_PART;
  int*   flag  = (int*)(ws + O_FLAG);
  bf16*  q2b   = (bf16*)(ws + O_Q2);
  bf16*  kcb   = (bf16*)(ws + O_KC);
  bf16*  vtb   = (bf16*)(ws + O_VT);

  detect_kernel<<<dim3(1), dim3(64), 0, stream>>>(mu0, flag);
  setup_wc<<<dim3(20,20,3), dim3(16,16), 0, stream>>>(inw, qkvw, WcT, flag);
  setup_misc<<<dim3(408), dim3(256), 0, stream>>>(inw, inb, qkvb, outw, outb, lng, lnb, bc, owT, vec, flag);
  ln0_kernel<<<dim3(128), dim3(320), 0, stream>>>(mu0, vec, alpha, d_out, flag);

  for (int t = 0; t < TM1_; ++t){
    project_kernel<<<dim3(3,32), dim3(320), 0, stream>>>(alpha, WcT, bc, q2b, kcb, vtb, t);
    int S = (t+1)*K_;
    int nch = (S + 255) / 256; if (nch > MAXCH_) nch = MAXCH_;
    int chunkS = (((S + nch - 1)/nch) + 127) / 128 * 128;
    int nchU = (S + chunkS - 1) / chunkS;
    attn_mfma<<<dim3(nchU, H_), dim3(512), 0, stream>>>(q2b, kcb, vtb, part, S, chunkS);
    combine_kernel<<<dim3(128), dim3(320), 0, stream>>>(part, owT, vec, alpha, d_out, flag, t, nchU);
  }
}